// Round 2
// baseline (1959.655 us; speedup 1.0000x reference)
//
#include <hip/hip_runtime.h>
#include <math.h>

// Problem constants
#define B_SZ 2
#define SEQ 2048
#define DMODEL 1024
#define NH 16
#define DK 64
#define NQKV 3072          // 3 * DMODEL
#define M_ROWS 4096        // B_SZ * SEQ

#define NEG_BIG (-3.0e38f)

// ---------------------------------------------------------------------------
// Kernel 1: QKV projection GEMM (M=4096, N=3072, K=1024) + RoPE + scatter
// proj[m][e] = sum_d x[m][d] * Wa[e][d];  e = which*1024 + h*64 + d
// Q,K get RoPE (coeffs read from rope matrix buffer), stored [B,H,S,DK].
// ---------------------------------------------------------------------------
__global__ __launch_bounds__(256) void qkv_rope_kernel(
    const float* __restrict__ x,     // [4096,1024]
    const float* __restrict__ Wa,    // [3072,1024]
    const float* __restrict__ rope,  // [2048,64,64]
    const int*  __restrict__ tpos,   // [2048]
    float* __restrict__ Qb, float* __restrict__ Kb, float* __restrict__ Vb)
{
    __shared__ float As[16][68];   // [k][m], padded stride 68 (16B-aligned rows)
    __shared__ float Bs[16][68];   // [k][n]

    const int tid = threadIdx.x;
    const int tm = tid >> 4;           // 0..15
    const int tn = tid & 15;           // 0..15
    const int m0 = blockIdx.y * 64;
    const int e0 = blockIdx.x * 64;

    const int lr = tid >> 2;           // 0..63 (row within tile)
    const int lc = (tid & 3) * 4;      // 0,4,8,12 (k offset within 16-wide k-block)

    float acc[4][4] = {};

    for (int k0 = 0; k0 < DMODEL; k0 += 16) {
        const float4 av = *reinterpret_cast<const float4*>(&x[(size_t)(m0 + lr) * DMODEL + k0 + lc]);
        const float4 bv = *reinterpret_cast<const float4*>(&Wa[(size_t)(e0 + lr) * DMODEL + k0 + lc]);
        __syncthreads();
        As[lc + 0][lr] = av.x; As[lc + 1][lr] = av.y; As[lc + 2][lr] = av.z; As[lc + 3][lr] = av.w;
        Bs[lc + 0][lr] = bv.x; Bs[lc + 1][lr] = bv.y; Bs[lc + 2][lr] = bv.z; Bs[lc + 3][lr] = bv.w;
        __syncthreads();
#pragma unroll
        for (int kk = 0; kk < 16; ++kk) {
            const float4 a4 = *reinterpret_cast<const float4*>(&As[kk][tm * 4]);
            const float4 b4 = *reinterpret_cast<const float4*>(&Bs[kk][tn * 4]);
            const float a[4] = {a4.x, a4.y, a4.z, a4.w};
            const float b[4] = {b4.x, b4.y, b4.z, b4.w};
#pragma unroll
            for (int i = 0; i < 4; ++i)
#pragma unroll
                for (int j = 0; j < 4; ++j)
                    acc[i][j] = fmaf(a[i], b[j], acc[i][j]);
        }
    }

    // Epilogue: tile spans exactly one (which, h) since e0 % 64 == 0.
    const int which = e0 >> 10;            // 0=Q,1=K,2=V
    const int h = (e0 & 1023) >> 6;
    const int d0 = tn * 4;                 // even, pairs contained in the 4 cols

    float* buf = (which == 0) ? Qb : ((which == 1) ? Kb : Vb);

#pragma unroll
    for (int i = 0; i < 4; ++i) {
        const int m = m0 + tm * 4 + i;
        const int b = m >> 11;             // / 2048
        const int s = m & 2047;
        float v0 = acc[i][0], v1 = acc[i][1], v2 = acc[i][2], v3 = acc[i][3];
        if (which < 2) {
            const int p = tpos[s];
            const float* Rp = rope + (size_t)p * 4096;
            // pair (d0, d0+1)
            {
                const int d = d0;
                const float c0 = Rp[d * 64 + d];
                const float c1 = Rp[(d + 1) * 64 + (d + 1)];
                const float sn = Rp[(d + 1) * 64 + d];
                const float q0 = v0, q1 = v1;
                v0 = c0 * q0 - sn * q1;
                v1 = sn * q0 + c1 * q1;
            }
            // pair (d0+2, d0+3)
            {
                const int d = d0 + 2;
                const float c0 = Rp[d * 64 + d];
                const float c1 = Rp[(d + 1) * 64 + (d + 1)];
                const float sn = Rp[(d + 1) * 64 + d];
                const float q0 = v2, q1 = v3;
                v2 = c0 * q0 - sn * q1;
                v3 = sn * q0 + c1 * q1;
            }
        }
        float4 o4; o4.x = v0; o4.y = v1; o4.z = v2; o4.w = v3;
        *reinterpret_cast<float4*>(&buf[(((size_t)b * NH + h) * SEQ + s) * DK + d0]) = o4;
    }
}

// ---------------------------------------------------------------------------
// Kernel 2: causal flash attention (fp32). One block = (b, h, 64-row Q tile).
// LDS: Qs [d][r], KPs [d][c] (reused as P^T [c][r]), Vs [c][d].
// FIX vs R1: 64x64 tiles need 16 floats staged per thread (4x float4 at
// column offsets lc+{0,16,32,48}) — previous version staged only dims 0..15
// and computed on stale LDS for dims 16..63.
// ---------------------------------------------------------------------------
__device__ inline float redmax16(float v) {
#pragma unroll
    for (int o = 8; o >= 1; o >>= 1) v = fmaxf(v, __shfl_xor(v, o, 64));
    return v;
}
__device__ inline float redsum16(float v) {
#pragma unroll
    for (int o = 8; o >= 1; o >>= 1) v += __shfl_xor(v, o, 64);
    return v;
}

__global__ __launch_bounds__(256) void attn_kernel(
    const float* __restrict__ Qb, const float* __restrict__ Kb,
    const float* __restrict__ Vb, float* __restrict__ att)
{
    __shared__ float Qs[64][68];
    __shared__ float KPs[64][68];
    __shared__ float Vs[64][68];

    const int tid = threadIdx.x;
    const int tm = tid >> 4;
    const int tn = tid & 15;
    const int it = blockIdx.x;       // Q tile 0..31
    const int h = blockIdx.y;
    const int b = blockIdx.z;

    const size_t headoff = ((size_t)b * NH + h) * SEQ * DK;
    const float* Qh = Qb + headoff;
    const float* Kh = Kb + headoff;
    const float* Vh = Vb + headoff;

    const int q0 = it * 64;
    const int lr = tid >> 2;           // 0..63 (row)
    const int lc = (tid & 3) * 4;      // 0,4,8,12 (base column)

    // Stage Q tile transposed [d][r] — 16 floats per thread
#pragma unroll
    for (int q = 0; q < 4; ++q) {
        const int c = lc + 16 * q;
        const float4 qv = *reinterpret_cast<const float4*>(&Qh[(size_t)(q0 + lr) * DK + c]);
        Qs[c + 0][lr] = qv.x; Qs[c + 1][lr] = qv.y; Qs[c + 2][lr] = qv.z; Qs[c + 3][lr] = qv.w;
    }

    float m_i[4] = {NEG_BIG, NEG_BIG, NEG_BIG, NEG_BIG};
    float l_i[4] = {0.f, 0.f, 0.f, 0.f};
    float O[4][4] = {};

    for (int jt = 0; jt <= it; ++jt) {
        const int c0 = jt * 64;
        float4 kv[4], vv[4];
#pragma unroll
        for (int q = 0; q < 4; ++q) {
            const int c = lc + 16 * q;
            kv[q] = *reinterpret_cast<const float4*>(&Kh[(size_t)(c0 + lr) * DK + c]);
            vv[q] = *reinterpret_cast<const float4*>(&Vh[(size_t)(c0 + lr) * DK + c]);
        }
        __syncthreads();   // (a) prior PV reads of KPs/Vs finished (covers Q staging too)
#pragma unroll
        for (int q = 0; q < 4; ++q) {
            const int c = lc + 16 * q;
            KPs[c + 0][lr] = kv[q].x; KPs[c + 1][lr] = kv[q].y;
            KPs[c + 2][lr] = kv[q].z; KPs[c + 3][lr] = kv[q].w;
            *reinterpret_cast<float4*>(&Vs[lr][c]) = vv[q];
        }
        __syncthreads();   // (b) K/V staged

        // S = Q K^T
        float sacc[4][4] = {};
#pragma unroll
        for (int dd = 0; dd < 64; ++dd) {
            const float4 qa = *reinterpret_cast<const float4*>(&Qs[dd][tm * 4]);
            const float4 kb = *reinterpret_cast<const float4*>(&KPs[dd][tn * 4]);
            const float a[4] = {qa.x, qa.y, qa.z, qa.w};
            const float c[4] = {kb.x, kb.y, kb.z, kb.w};
#pragma unroll
            for (int i = 0; i < 4; ++i)
#pragma unroll
                for (int j = 0; j < 4; ++j)
                    sacc[i][j] = fmaf(a[i], c[j], sacc[i][j]);
        }

        // scale + causal mask
#pragma unroll
        for (int i = 0; i < 4; ++i) {
            const int rg = q0 + tm * 4 + i;
#pragma unroll
            for (int j = 0; j < 4; ++j) {
                const int cg = c0 + tn * 4 + j;
                sacc[i][j] = (cg > rg) ? NEG_BIG : sacc[i][j] * 0.125f;
            }
        }

        // online softmax update (rows live in 16 consecutive lanes)
        float alpha[4];
#pragma unroll
        for (int i = 0; i < 4; ++i) {
            float rm = fmaxf(fmaxf(sacc[i][0], sacc[i][1]), fmaxf(sacc[i][2], sacc[i][3]));
            rm = redmax16(rm);
            const float mnew = fmaxf(m_i[i], rm);
            alpha[i] = expf(m_i[i] - mnew);
            float rs = 0.f;
#pragma unroll
            for (int j = 0; j < 4; ++j) {
                const float p = expf(sacc[i][j] - mnew);
                sacc[i][j] = p;
                rs += p;
            }
            rs = redsum16(rs);
            l_i[i] = l_i[i] * alpha[i] + rs;
            m_i[i] = mnew;
#pragma unroll
            for (int j = 0; j < 4; ++j) O[i][j] *= alpha[i];
        }

        __syncthreads();   // (c) all S-GEMM reads of KPs done before P overwrite
#pragma unroll
        for (int i = 0; i < 4; ++i)
#pragma unroll
            for (int j = 0; j < 4; ++j)
                KPs[tn * 4 + j][tm * 4 + i] = sacc[i][j];   // P^T: [c][r]
        __syncthreads();   // (d) P staged

        // O += P V
#pragma unroll
        for (int cc = 0; cc < 64; ++cc) {
            const float4 pa = *reinterpret_cast<const float4*>(&KPs[cc][tm * 4]);
            const float4 vb = *reinterpret_cast<const float4*>(&Vs[cc][tn * 4]);
            const float a[4] = {pa.x, pa.y, pa.z, pa.w};
            const float c[4] = {vb.x, vb.y, vb.z, vb.w};
#pragma unroll
            for (int i = 0; i < 4; ++i)
#pragma unroll
                for (int j = 0; j < 4; ++j)
                    O[i][j] = fmaf(a[i], c[j], O[i][j]);
        }
    }

    // epilogue: divide by l, store to att[b][s][h*64+d]
#pragma unroll
    for (int i = 0; i < 4; ++i) {
        const float inv = 1.0f / l_i[i];
        const int s = q0 + tm * 4 + i;
        float4 o4;
        o4.x = O[i][0] * inv; o4.y = O[i][1] * inv; o4.z = O[i][2] * inv; o4.w = O[i][3] * inv;
        *reinterpret_cast<float4*>(&att[((size_t)b * SEQ + s) * DMODEL + h * DK + tn * 4]) = o4;
    }
}

// ---------------------------------------------------------------------------
// Kernel 3: output projection GEMM (M=4096, N=1024, K=1024)
// out[m][n] = sum_e att[m][e] * Wo[n][e]
// ---------------------------------------------------------------------------
__global__ __launch_bounds__(256) void out_proj_kernel(
    const float* __restrict__ att,  // [4096,1024]
    const float* __restrict__ Wo,   // [1024,1024]
    float* __restrict__ out)        // [4096,1024]
{
    __shared__ float As[16][68];
    __shared__ float Bs[16][68];

    const int tid = threadIdx.x;
    const int tm = tid >> 4;
    const int tn = tid & 15;
    const int m0 = blockIdx.y * 64;
    const int n0 = blockIdx.x * 64;

    const int lr = tid >> 2;
    const int lc = (tid & 3) * 4;

    float acc[4][4] = {};

    for (int k0 = 0; k0 < DMODEL; k0 += 16) {
        const float4 av = *reinterpret_cast<const float4*>(&att[(size_t)(m0 + lr) * DMODEL + k0 + lc]);
        const float4 bv = *reinterpret_cast<const float4*>(&Wo[(size_t)(n0 + lr) * DMODEL + k0 + lc]);
        __syncthreads();
        As[lc + 0][lr] = av.x; As[lc + 1][lr] = av.y; As[lc + 2][lr] = av.z; As[lc + 3][lr] = av.w;
        Bs[lc + 0][lr] = bv.x; Bs[lc + 1][lr] = bv.y; Bs[lc + 2][lr] = bv.z; Bs[lc + 3][lr] = bv.w;
        __syncthreads();
#pragma unroll
        for (int kk = 0; kk < 16; ++kk) {
            const float4 a4 = *reinterpret_cast<const float4*>(&As[kk][tm * 4]);
            const float4 b4 = *reinterpret_cast<const float4*>(&Bs[kk][tn * 4]);
            const float a[4] = {a4.x, a4.y, a4.z, a4.w};
            const float b[4] = {b4.x, b4.y, b4.z, b4.w};
#pragma unroll
            for (int i = 0; i < 4; ++i)
#pragma unroll
                for (int j = 0; j < 4; ++j)
                    acc[i][j] = fmaf(a[i], b[j], acc[i][j]);
        }
    }

#pragma unroll
    for (int i = 0; i < 4; ++i) {
        const int m = m0 + tm * 4 + i;
        float4 o4;
        o4.x = acc[i][0]; o4.y = acc[i][1]; o4.z = acc[i][2]; o4.w = acc[i][3];
        *reinterpret_cast<float4*>(&out[(size_t)m * DMODEL + n0 + tn * 4]) = o4;
    }
}

// ---------------------------------------------------------------------------
extern "C" void kernel_launch(void* const* d_in, const int* in_sizes, int n_in,
                              void* d_out, int out_size, void* d_ws, size_t ws_size,
                              hipStream_t stream) {
    (void)in_sizes; (void)n_in; (void)out_size; (void)ws_size;

    const float* x    = (const float*)d_in[0];   // [2,2048,1024]
    const float* Wa   = (const float*)d_in[1];   // [3072,1024]
    const float* Wo   = (const float*)d_in[2];   // [1024,1024]
    const float* rope = (const float*)d_in[3];   // [2048,64,64]
    const int*   tp   = (const int*)d_in[4];     // [2048]
    float* out = (float*)d_out;

    float* ws = (float*)d_ws;
    const size_t HEADBUF = (size_t)B_SZ * NH * SEQ * DK;  // 4,194,304 floats
    float* Qb  = ws;
    float* Kb  = ws + HEADBUF;
    float* Vb  = ws + 2 * HEADBUF;
    float* att = ws + 3 * HEADBUF;                        // [4096,1024]

    dim3 blk(256);
    qkv_rope_kernel<<<dim3(NQKV / 64, M_ROWS / 64), blk, 0, stream>>>(x, Wa, rope, tp, Qb, Kb, Vb);
    attn_kernel<<<dim3(SEQ / 64, NH, B_SZ), blk, 0, stream>>>(Qb, Kb, Vb, att);
    out_proj_kernel<<<dim3(DMODEL / 64, M_ROWS / 64), blk, 0, stream>>>(att, Wo, out);
}

// Round 3
// 361.630 us; speedup vs baseline: 5.4190x; 5.4190x over previous
//
#include <hip/hip_runtime.h>
#include <math.h>

// Problem constants
#define B_SZ 2
#define SEQ 2048
#define DMODEL 1024
#define NH 16
#define DK 64
#define NQKV 3072
#define M_ROWS 4096

#define NEG_BIG (-3.0e38f)

typedef short short8 __attribute__((ext_vector_type(8)));
typedef float v4f __attribute__((ext_vector_type(4)));
typedef unsigned short ushort_t;

__device__ inline ushort_t f2bf(float f) {
    unsigned u = __float_as_uint(f);
    u += 0x7fffu + ((u >> 16) & 1u);   // RNE
    return (ushort_t)(u >> 16);
}

// ---------------------------------------------------------------------------
// Kernel 0a: fp32 -> bf16 convert (vector of 4)
// ---------------------------------------------------------------------------
__global__ __launch_bounds__(256) void cvt_bf16_kernel(
    const float* __restrict__ src, ushort_t* __restrict__ dst, int n4)
{
    int i = blockIdx.x * 256 + threadIdx.x;
    if (i < n4) {
        float4 v = reinterpret_cast<const float4*>(src)[i];
        ushort4 r;
        r.x = f2bf(v.x); r.y = f2bf(v.y); r.z = f2bf(v.z); r.w = f2bf(v.w);
        reinterpret_cast<ushort4*>(dst)[i] = r;
    }
}

// ---------------------------------------------------------------------------
// Kernel 0b: extract RoPE cos/sin tables from the [2048,64,64] matrix buffer.
// cosT[p*64+d] = R[p][d][d];  sinT[p*64+d] = +-R[p][d|1][d&~1]
// so that rotated v' = cosT[d]*v + sinT[d]*pair(v), pair = shfl_xor(v,1).
// ---------------------------------------------------------------------------
__global__ __launch_bounds__(256) void rope_table_kernel(
    const float* __restrict__ rope, float* __restrict__ cosT, float* __restrict__ sinT)
{
    int i = blockIdx.x * 256 + threadIdx.x;   // [0, 2048*64)
    int p = i >> 6, d = i & 63;
    const float* Rp = rope + (size_t)p * 4096;
    float c = Rp[d * 64 + d];
    float s = Rp[(d | 1) * 64 + (d & ~1)];
    cosT[i] = c;
    sinT[i] = (d & 1) ? s : -s;
}

// ---------------------------------------------------------------------------
// MFMA bt-GEMM core: C[m][n] = sum_k A[m][k] B[n][k], bf16 in, fp32 acc.
// Block tile 128x128, BK=32, 4 waves in 2x2 (each wave 64x64 via 4x4 frags).
// Fragment layouts (verified, learn_hip m89/m91):
//   A/B operand: idx = lane&15, k = (lane>>4)*8 + j
//   C/D:         col = lane&15, row = (lane>>4)*4 + reg
// ---------------------------------------------------------------------------

// Kernel 1: QKV projection + RoPE epilogue -> Q/K/V bf16 [B,H,S,DK]
__global__ __launch_bounds__(256) void qkv_mfma_kernel(
    const ushort_t* __restrict__ xb,   // [4096,1024] bf16
    const ushort_t* __restrict__ Wab,  // [3072,1024] bf16
    const float* __restrict__ cosT, const float* __restrict__ sinT,
    const int* __restrict__ tpos,
    ushort_t* __restrict__ Qb, ushort_t* __restrict__ Kb, ushort_t* __restrict__ Vb)
{
    __shared__ ushort_t As[128][40];   // [m][k] pad 32->40 (80B rows, 16B-aligned)
    __shared__ ushort_t Bs[128][40];   // [n][k]

    const int tid = threadIdx.x;
    const int w = tid >> 6, lane = tid & 63;
    const int lm = lane & 15, g = lane >> 4, lk8 = g * 8;
    const int wm = (w >> 1) * 64, wn = (w & 1) * 64;
    const int m0 = blockIdx.y * 128, n0 = blockIdx.x * 128;

    v4f acc[4][4] = {};

    for (int k0 = 0; k0 < DMODEL; k0 += 32) {
        // stage: 512 16B-chunks per tile, 2 per thread per tile
        short8 a[2], b[2];
#pragma unroll
        for (int rep = 0; rep < 2; ++rep) {
            const int c = tid + 256 * rep;
            const int r = c >> 2, q8 = (c & 3) * 8;
            a[rep] = *reinterpret_cast<const short8*>(&xb [(size_t)(m0 + r) * DMODEL + k0 + q8]);
            b[rep] = *reinterpret_cast<const short8*>(&Wab[(size_t)(n0 + r) * DMODEL + k0 + q8]);
        }
        __syncthreads();
#pragma unroll
        for (int rep = 0; rep < 2; ++rep) {
            const int c = tid + 256 * rep;
            const int r = c >> 2, q8 = (c & 3) * 8;
            *reinterpret_cast<short8*>(&As[r][q8]) = a[rep];
            *reinterpret_cast<short8*>(&Bs[r][q8]) = b[rep];
        }
        __syncthreads();

        short8 af[4], bfr[4];
#pragma unroll
        for (int mf = 0; mf < 4; ++mf) af[mf]  = *reinterpret_cast<const short8*>(&As[wm + mf * 16 + lm][lk8]);
#pragma unroll
        for (int nf = 0; nf < 4; ++nf) bfr[nf] = *reinterpret_cast<const short8*>(&Bs[wn + nf * 16 + lm][lk8]);
#pragma unroll
        for (int mf = 0; mf < 4; ++mf)
#pragma unroll
            for (int nf = 0; nf < 4; ++nf)
                acc[mf][nf] = __builtin_amdgcn_mfma_f32_16x16x32_bf16(af[mf], bfr[nf], acc[mf][nf], 0, 0, 0);
    }

    // epilogue: RoPE (Q,K) + scatter to [B,H,S,DK] bf16
    const int which = n0 >> 10;            // block-uniform (128 | 1024)
    ushort_t* buf = (which == 0) ? Qb : ((which == 1) ? Kb : Vb);
    const int nbase = n0 + wn;

#pragma unroll
    for (int mf = 0; mf < 4; ++mf) {
#pragma unroll
        for (int reg = 0; reg < 4; ++reg) {
            const int m = m0 + wm + mf * 16 + g * 4 + reg;
            const int bb = m >> 11, s = m & 2047;
            const int p = tpos[s];
#pragma unroll
            for (int nf = 0; nf < 4; ++nf) {
                const int n = nbase + nf * 16 + lm;
                const int h = (n >> 6) & 15;
                const int d = n & 63;
                float v = acc[mf][nf][reg];
                if (which < 2) {
                    const float pr = __shfl_xor(v, 1, 64);
                    v = cosT[p * 64 + d] * v + sinT[p * 64 + d] * pr;
                }
                buf[(((size_t)bb * NH + h) * SEQ + s) * DK + d] = f2bf(v);
            }
        }
    }
}

// ---------------------------------------------------------------------------
// Kernel 2: flash attention, bf16 MFMA. Block = (q-tile 64, h, b), 4 waves,
// wave w owns q rows [q0+16w, q0+16w+16). kv tiles of 64.
// K fragments direct from global; V transposed via LDS; P via LDS roundtrip.
// ---------------------------------------------------------------------------
__global__ __launch_bounds__(256) void attn_mfma_kernel(
    const ushort_t* __restrict__ Qb, const ushort_t* __restrict__ Kb,
    const ushort_t* __restrict__ Vb, ushort_t* __restrict__ attb)
{
    __shared__ ushort_t Vt[64][72];      // V^T tile [d][kv], rows 144B (16B-aligned)
    __shared__ ushort_t Ps[4][16][72];   // per-wave P [m][kv]

    const int tid = threadIdx.x;
    const int w = tid >> 6, lane = tid & 63;
    const int lm = lane & 15, g = lane >> 4, lk8 = g * 8;

    const int it = (SEQ / 64 - 1) - blockIdx.x;   // heavy tiles first
    const int h = blockIdx.y, b = blockIdx.z;
    const size_t ho = ((size_t)b * NH + h) * SEQ * DK;
    const ushort_t* Qh = Qb + ho;
    const ushort_t* Kh = Kb + ho;
    const ushort_t* Vh = Vb + ho;

    const int q0 = it * 64;
    const int qrow = q0 + w * 16 + lm;

    short8 qf[2];
    qf[0] = *reinterpret_cast<const short8*>(&Qh[(size_t)qrow * DK + 0 + lk8]);
    qf[1] = *reinterpret_cast<const short8*>(&Qh[(size_t)qrow * DK + 32 + lk8]);

    float m_i[4] = {NEG_BIG, NEG_BIG, NEG_BIG, NEG_BIG};
    float l_i[4] = {0.f, 0.f, 0.f, 0.f};
    v4f Oa[4] = {};

    for (int jt = 0; jt <= it; ++jt) {
        const int c0 = jt * 64;

        // load V rows (coalesced), then transpose into LDS
        short8 vv[2];
        int kvr[2], d8r[2];
#pragma unroll
        for (int rep = 0; rep < 2; ++rep) {
            const int c = tid + 256 * rep;
            kvr[rep] = c & 63; d8r[rep] = (c >> 6) * 8;
            vv[rep] = *reinterpret_cast<const short8*>(&Vh[(size_t)(c0 + kvr[rep]) * DK + d8r[rep]]);
        }
        __syncthreads();   // prior PV reads of Vt/Ps complete
#pragma unroll
        for (int rep = 0; rep < 2; ++rep)
#pragma unroll
            for (int j = 0; j < 8; ++j)
                Vt[d8r[rep] + j][kvr[rep]] = (ushort_t)vv[rep][j];

        // S = Q K^T  (K fragments from global; L1/L2-served)
        v4f sacc[4] = {};
#pragma unroll
        for (int nf = 0; nf < 4; ++nf) {
#pragma unroll
            for (int kb = 0; kb < 2; ++kb) {
                const short8 kf = *reinterpret_cast<const short8*>(
                    &Kh[(size_t)(c0 + nf * 16 + lm) * DK + kb * 32 + lk8]);
                sacc[nf] = __builtin_amdgcn_mfma_f32_16x16x32_bf16(qf[kb], kf, sacc[nf], 0, 0, 0);
            }
        }

        // scale + causal mask (diagonal tile only)
        const bool diag = (jt == it);
#pragma unroll
        for (int nf = 0; nf < 4; ++nf)
#pragma unroll
            for (int reg = 0; reg < 4; ++reg) {
                float sv = sacc[nf][reg] * 0.125f;
                if (diag) {
                    const int cg = c0 + nf * 16 + lm;
                    const int rg = q0 + w * 16 + g * 4 + reg;
                    if (cg > rg) sv = NEG_BIG;
                }
                sacc[nf][reg] = sv;
            }

        // online softmax (rows: reg; cols: 16 lanes x 4 nf)
        float alpha[4];
#pragma unroll
        for (int reg = 0; reg < 4; ++reg) {
            float rm = fmaxf(fmaxf(sacc[0][reg], sacc[1][reg]), fmaxf(sacc[2][reg], sacc[3][reg]));
#pragma unroll
            for (int o = 8; o >= 1; o >>= 1) rm = fmaxf(rm, __shfl_xor(rm, o, 64));
            const float mnew = fmaxf(m_i[reg], rm);
            alpha[reg] = __expf(m_i[reg] - mnew);
            float rs = 0.f;
#pragma unroll
            for (int nf = 0; nf < 4; ++nf) {
                const float p = __expf(sacc[nf][reg] - mnew);
                sacc[nf][reg] = p;
                rs += p;
            }
#pragma unroll
            for (int o = 8; o >= 1; o >>= 1) rs += __shfl_xor(rs, o, 64);
            l_i[reg] = l_i[reg] * alpha[reg] + rs;
            m_i[reg] = mnew;
#pragma unroll
            for (int nf = 0; nf < 4; ++nf) Oa[nf][reg] *= alpha[reg];
        }

        // P (C/D layout) -> LDS in A-operand-friendly [m][kv]
#pragma unroll
        for (int reg = 0; reg < 4; ++reg)
#pragma unroll
            for (int nf = 0; nf < 4; ++nf)
                Ps[w][g * 4 + reg][nf * 16 + lm] = f2bf(sacc[nf][reg]);
        __syncthreads();   // Vt + Ps staged for everyone

        // O += P V
        short8 pf[2];
        pf[0] = *reinterpret_cast<const short8*>(&Ps[w][lm][0 + lk8]);
        pf[1] = *reinterpret_cast<const short8*>(&Ps[w][lm][32 + lk8]);
#pragma unroll
        for (int nf = 0; nf < 4; ++nf) {
#pragma unroll
            for (int kc = 0; kc < 2; ++kc) {
                const short8 vf = *reinterpret_cast<const short8*>(&Vt[nf * 16 + lm][kc * 32 + lk8]);
                Oa[nf] = __builtin_amdgcn_mfma_f32_16x16x32_bf16(pf[kc], vf, Oa[nf], 0, 0, 0);
            }
        }
    }

    // epilogue: normalize, store bf16 att[b][s][h*64+d]
    float inv[4];
#pragma unroll
    for (int reg = 0; reg < 4; ++reg) inv[reg] = 1.0f / l_i[reg];
#pragma unroll
    for (int nf = 0; nf < 4; ++nf)
#pragma unroll
        for (int reg = 0; reg < 4; ++reg) {
            const int s = q0 + w * 16 + g * 4 + reg;
            attb[((size_t)b * SEQ + s) * DMODEL + h * DK + nf * 16 + lm] = f2bf(Oa[nf][reg] * inv[reg]);
        }
}

// ---------------------------------------------------------------------------
// Kernel 3: output projection, bf16 MFMA, fp32 out.
// ---------------------------------------------------------------------------
__global__ __launch_bounds__(256) void out_mfma_kernel(
    const ushort_t* __restrict__ attb,  // [4096,1024] bf16
    const ushort_t* __restrict__ Wob,   // [1024,1024] bf16
    float* __restrict__ out)            // [4096,1024] fp32
{
    __shared__ ushort_t As[128][40];
    __shared__ ushort_t Bs[128][40];

    const int tid = threadIdx.x;
    const int w = tid >> 6, lane = tid & 63;
    const int lm = lane & 15, g = lane >> 4, lk8 = g * 8;
    const int wm = (w >> 1) * 64, wn = (w & 1) * 64;
    const int m0 = blockIdx.y * 128, n0 = blockIdx.x * 128;

    v4f acc[4][4] = {};

    for (int k0 = 0; k0 < DMODEL; k0 += 32) {
        short8 a[2], b[2];
#pragma unroll
        for (int rep = 0; rep < 2; ++rep) {
            const int c = tid + 256 * rep;
            const int r = c >> 2, q8 = (c & 3) * 8;
            a[rep] = *reinterpret_cast<const short8*>(&attb[(size_t)(m0 + r) * DMODEL + k0 + q8]);
            b[rep] = *reinterpret_cast<const short8*>(&Wob [(size_t)(n0 + r) * DMODEL + k0 + q8]);
        }
        __syncthreads();
#pragma unroll
        for (int rep = 0; rep < 2; ++rep) {
            const int c = tid + 256 * rep;
            const int r = c >> 2, q8 = (c & 3) * 8;
            *reinterpret_cast<short8*>(&As[r][q8]) = a[rep];
            *reinterpret_cast<short8*>(&Bs[r][q8]) = b[rep];
        }
        __syncthreads();

        short8 af[4], bfr[4];
#pragma unroll
        for (int mf = 0; mf < 4; ++mf) af[mf]  = *reinterpret_cast<const short8*>(&As[wm + mf * 16 + lm][lk8]);
#pragma unroll
        for (int nf = 0; nf < 4; ++nf) bfr[nf] = *reinterpret_cast<const short8*>(&Bs[wn + nf * 16 + lm][lk8]);
#pragma unroll
        for (int mf = 0; mf < 4; ++mf)
#pragma unroll
            for (int nf = 0; nf < 4; ++nf)
                acc[mf][nf] = __builtin_amdgcn_mfma_f32_16x16x32_bf16(af[mf], bfr[nf], acc[mf][nf], 0, 0, 0);
    }

#pragma unroll
    for (int mf = 0; mf < 4; ++mf)
#pragma unroll
        for (int reg = 0; reg < 4; ++reg) {
            const int m = m0 + wm + mf * 16 + g * 4 + reg;
#pragma unroll
            for (int nf = 0; nf < 4; ++nf) {
                const int n = n0 + wn + nf * 16 + lm;
                out[(size_t)m * DMODEL + n] = acc[mf][nf][reg];
            }
        }
}

// ---------------------------------------------------------------------------
extern "C" void kernel_launch(void* const* d_in, const int* in_sizes, int n_in,
                              void* d_out, int out_size, void* d_ws, size_t ws_size,
                              hipStream_t stream) {
    (void)in_sizes; (void)n_in; (void)out_size; (void)ws_size;

    const float* x    = (const float*)d_in[0];
    const float* Wa   = (const float*)d_in[1];
    const float* Wo   = (const float*)d_in[2];
    const float* rope = (const float*)d_in[3];
    const int*   tp   = (const int*)d_in[4];
    float* out = (float*)d_out;

    char* ws = (char*)d_ws;
    ushort_t* xb   = (ushort_t*)(ws);                       // 8 MB
    ushort_t* Wab  = (ushort_t*)(ws + (8u << 20));          // 6 MB
    ushort_t* Wob  = (ushort_t*)(ws + (14u << 20));         // 2 MB
    float*    cosT = (float*)   (ws + (16u << 20));         // 0.5 MB
    float*    sinT = (float*)   (ws + (16u << 20) + (512u << 10));
    ushort_t* Qb   = (ushort_t*)(ws + (17u << 20));         // 8 MB
    ushort_t* Kb   = (ushort_t*)(ws + (25u << 20));         // 8 MB
    ushort_t* Vb   = (ushort_t*)(ws + (33u << 20));         // 8 MB
    ushort_t* attb = (ushort_t*)(ws + (41u << 20));         // 8 MB

    dim3 blk(256);
    cvt_bf16_kernel<<<dim3((M_ROWS * DMODEL / 4) / 256), blk, 0, stream>>>(x,  xb,  M_ROWS * DMODEL / 4);
    cvt_bf16_kernel<<<dim3((NQKV  * DMODEL / 4) / 256), blk, 0, stream>>>(Wa, Wab, NQKV  * DMODEL / 4);
    cvt_bf16_kernel<<<dim3((DMODEL * DMODEL / 4) / 256), blk, 0, stream>>>(Wo, Wob, DMODEL * DMODEL / 4);
    rope_table_kernel<<<dim3(SEQ * DK / 256), blk, 0, stream>>>(rope, cosT, sinT);

    qkv_mfma_kernel<<<dim3(NQKV / 128, M_ROWS / 128), blk, 0, stream>>>(
        xb, Wab, cosT, sinT, tp, Qb, Kb, Vb);
    attn_mfma_kernel<<<dim3(SEQ / 64, NH, B_SZ), blk, 0, stream>>>(Qb, Kb, Vb, attb);
    out_mfma_kernel<<<dim3(DMODEL / 128, M_ROWS / 128), blk, 0, stream>>>(attb, Wob, out);
}